// Round 11
// baseline (448.185 us; speedup 1.0000x reference)
//
#include <hip/hip_runtime.h>
#include <math.h>

#define NN 50000
#define EE 1000000

#define LINB 782                        // ceil(50000/64) blocks of 64 rows
#define CNT_THREADS (EE / 4)            // 250000 int4 units
#define CNTB ((CNT_THREADS + 255) / 256)  // 977

typedef float f32x4 __attribute__((ext_vector_type(4)));
typedef __bf16 bf16x8 __attribute__((ext_vector_type(8)));

typedef __attribute__((address_space(1))) const void gvoid_t;
typedef __attribute__((address_space(3))) void svoid_t;

// ---------------- prep: W^T bf16, XOR-swizzled, linear 64KB image in global ----------------
// image[(c*256 + k*2) ^ ((c&7)<<4)] = bf16(W[k][c])  — exactly the LDS image lin reads.
__global__ __launch_bounds__(256) void prep_kernel(
    const float* __restrict__ Wl, const float* __restrict__ Wr, __bf16* __restrict__ img)
{
  const int c  = threadIdx.x;          // 0..255 output column
  const int cc = c & 127;
  const float* __restrict__ Wsrc = (c < 128) ? Wl : Wr;
  for (int k0 = 0; k0 < 128; k0 += 8) {
    bf16x8 v;
    #pragma unroll
    for (int j = 0; j < 8; ++j) v[j] = (__bf16)Wsrc[(size_t)(k0 + j) * 128 + cc];
    int byte = (c * 256 + k0 * 2) ^ ((c & 7) << 4);
    *(bf16x8*)((char*)img + byte) = v;
  }
}

// ---------------- fused: bf16-MFMA lin GEMM (x@[Wl|Wr]+[bl|br]) + count/rank ----------------
__global__ __launch_bounds__(256) void lin_count_kernel(
    const float* __restrict__ x,
    const __bf16* __restrict__ img,
    const float* __restrict__ bl, const float* __restrict__ br,
    float* __restrict__ xl, float* __restrict__ xr,
    const int* __restrict__ dst, int* __restrict__ counts, int* __restrict__ rank)
{
  const int tid = threadIdx.x;

  if (blockIdx.x >= LINB) {
    // ---- degree count + per-edge rank (single atomic pass) ----
    int t = (blockIdx.x - LINB) * 256 + tid;
    if (t < CNT_THREADS) {
      int4 d4 = ((const int4*)dst)[t];
      int4 r4;
      r4.x = atomicAdd(&counts[d4.x], 1);
      r4.y = atomicAdd(&counts[d4.y], 1);
      r4.z = atomicAdd(&counts[d4.z], 1);
      r4.w = atomicAdd(&counts[d4.w], 1);
      ((int4*)rank)[t] = r4;
    }
    return;
  }

  // ---- MFMA GEMM: C[64 rows][256 cols], cols 0-127 -> xl, 128-255 -> xr ----
  __shared__ __bf16 wt[256 * 128];   // 64 KB, linear copy of pre-swizzled image

  {
    const int wv = tid >> 6, ln = tid & 63;
    #pragma unroll
    for (int it = 0; it < 16; ++it) {
      int off = wv * 16384 + it * 1024;       // wave-uniform LDS offset
      __builtin_amdgcn_global_load_lds(
          (gvoid_t*)((const char*)img + off + ln * 16),
          (svoid_t*)((char*)wt + off), 16, 0, 0);
    }
  }
  __syncthreads();

  const int wave = tid >> 6;
  const int lane = tid & 63;
  const int l15  = lane & 15;
  const int lhi  = lane >> 4;   // 0..3

  const int row_a   = blockIdx.x * 64 + wave * 16 + l15;   // A-fragment row
  const int row_a_c = row_a < NN ? row_a : NN - 1;         // clamp (stores guarded)

  f32x4 acc[16];
  #pragma unroll
  for (int t = 0; t < 16; ++t) acc[t] = (f32x4)0.f;

  #pragma unroll
  for (int kk = 0; kk < 4; ++kk) {
    const float* ap = x + (size_t)row_a_c * 128 + kk * 32 + lhi * 8;
    float4 a0 = *(const float4*)ap;
    float4 a1 = *(const float4*)(ap + 4);
    bf16x8 af;
    af[0] = (__bf16)a0.x; af[1] = (__bf16)a0.y; af[2] = (__bf16)a0.z; af[3] = (__bf16)a0.w;
    af[4] = (__bf16)a1.x; af[5] = (__bf16)a1.y; af[6] = (__bf16)a1.z; af[7] = (__bf16)a1.w;
    #pragma unroll
    for (int nt = 0; nt < 16; ++nt) {
      int col  = nt * 16 + l15;
      int byte = (col * 256 + (kk * 32 + lhi * 8) * 2) ^ ((col & 7) << 4);
      bf16x8 bf = *(const bf16x8*)((const char*)wt + byte);
      acc[nt] = __builtin_amdgcn_mfma_f32_16x16x32_bf16(af, bf, acc[nt], 0, 0, 0);
    }
  }

  // epilogue: C layout col=lane&15, row=(lane>>4)*4+j  [m89-verified]
  const int row_base = blockIdx.x * 64 + wave * 16 + lhi * 4;
  #pragma unroll
  for (int nt = 0; nt < 16; ++nt) {
    int col = nt * 16 + l15;
    float bv = (col < 128) ? bl[col] : br[col - 128];
    float* dp = (col < 128) ? (xl + col) : (xr + (col - 128));
    #pragma unroll
    for (int j = 0; j < 4; ++j) {
      int r = row_base + j;
      if (r < NN) dp[(size_t)r * 128] = acc[nt][j] + bv;
    }
  }
}

// ---------------- scan: exclusive prefix over counts -> row_ptr ----------------
__global__ __launch_bounds__(1024) void scan_kernel(const int* __restrict__ counts,
                                                    int* __restrict__ row_ptr)
{
  __shared__ int s[1024];
  const int t = threadIdx.x;
  const int CH = (NN + 1023) / 1024;   // 49
  const int base = t * CH;
  int sum = 0;
  for (int j = 0; j < CH; ++j) {
    int idx = base + j;
    if (idx < NN) sum += counts[idx];
  }
  s[t] = sum;
  __syncthreads();
  for (int ofs = 1; ofs < 1024; ofs <<= 1) {
    int v = (t >= ofs) ? s[t - ofs] : 0;
    __syncthreads();
    s[t] += v;
    __syncthreads();
  }
  int run = s[t] - sum;
  for (int j = 0; j < CH; ++j) {
    int idx = base + j;
    if (idx < NN) { row_ptr[idx] = run; run += counts[idx]; }
  }
  if (t == 1023) row_ptr[NN] = s[1023];
}

// ---------------- fill: atomic-free placement via rank ----------------
__global__ __launch_bounds__(256) void fill_kernel(const int* __restrict__ src,
                                                   const int* __restrict__ dst,
                                                   const int* __restrict__ rank,
                                                   const int* __restrict__ row_ptr,
                                                   int2* __restrict__ csr)
{
  int t = blockIdx.x * 256 + threadIdx.x;
  if (t >= CNT_THREADS) return;
  int4 s4 = ((const int4*)src)[t];
  int4 d4 = ((const int4*)dst)[t];
  int4 r4 = ((const int4*)rank)[t];
  int e0 = t * 4;
  csr[row_ptr[d4.x] + r4.x] = make_int2(s4.x, e0 + 0);
  csr[row_ptr[d4.y] + r4.y] = make_int2(s4.y, e0 + 1);
  csr[row_ptr[d4.z] + r4.z] = make_int2(s4.z, e0 + 2);
  csr[row_ptr[d4.w] + r4.w] = make_int2(s4.w, e0 + 3);
}

// ---------------- fused per-node kernel ----------------
template<int CTRL>
__device__ __forceinline__ float dpp_add(float v)
{
  int y = __builtin_amdgcn_update_dpp(0, __float_as_int(v), CTRL, 0xF, 0xF, true);
  return v + __int_as_float(y);
}

__device__ __forceinline__ float head_reduce32(float v)
{
  v = dpp_add<0xB1>(v);    // quad_perm xor1
  v = dpp_add<0x4E>(v);    // quad_perm xor2
  v = dpp_add<0x141>(v);   // row_half_mirror
  v = dpp_add<0x140>(v);   // row_mirror
  int y = __builtin_amdgcn_ds_swizzle(__float_as_int(v), 0x401F); // xor16 within 32
  return v + __int_as_float(y);
}

__device__ __forceinline__ void edge_compute(
    float v0, float v1, float4 e0, float4 e1, float4 e2, float4 e3,
    float4 Wa0, float4 Wa1, float4 Wa2, float4 Wa3,
    float4 Wb0, float4 Wb1, float4 Wb2, float4 Wb3,
    float att0, float att1, float xr0, float xr1,
    float& S0, float& S1, float& A0, float& A1)
{
  float s0 = xr0, s1 = xr1;
  s0 = fmaf(e0.x, Wa0.x, s0); s1 = fmaf(e0.x, Wb0.x, s1);
  s0 = fmaf(e0.y, Wa0.y, s0); s1 = fmaf(e0.y, Wb0.y, s1);
  s0 = fmaf(e0.z, Wa0.z, s0); s1 = fmaf(e0.z, Wb0.z, s1);
  s0 = fmaf(e0.w, Wa0.w, s0); s1 = fmaf(e0.w, Wb0.w, s1);
  s0 = fmaf(e1.x, Wa1.x, s0); s1 = fmaf(e1.x, Wb1.x, s1);
  s0 = fmaf(e1.y, Wa1.y, s0); s1 = fmaf(e1.y, Wb1.y, s1);
  s0 = fmaf(e1.z, Wa1.z, s0); s1 = fmaf(e1.z, Wb1.z, s1);
  s0 = fmaf(e1.w, Wa1.w, s0); s1 = fmaf(e1.w, Wb1.w, s1);
  s0 = fmaf(e2.x, Wa2.x, s0); s1 = fmaf(e2.x, Wb2.x, s1);
  s0 = fmaf(e2.y, Wa2.y, s0); s1 = fmaf(e2.y, Wb2.y, s1);
  s0 = fmaf(e2.z, Wa2.z, s0); s1 = fmaf(e2.z, Wb2.z, s1);
  s0 = fmaf(e2.w, Wa2.w, s0); s1 = fmaf(e2.w, Wb2.w, s1);
  s0 = fmaf(e3.x, Wa3.x, s0); s1 = fmaf(e3.x, Wb3.x, s1);
  s0 = fmaf(e3.y, Wa3.y, s0); s1 = fmaf(e3.y, Wb3.y, s1);
  s0 = fmaf(e3.z, Wa3.z, s0); s1 = fmaf(e3.z, Wb3.z, s1);
  s0 = fmaf(e3.w, Wa3.w, s0); s1 = fmaf(e3.w, Wb3.w, s1);

  float u0 = v0 + s0;
  float u1 = v1 + s1;
  u0 = fmaxf(u0, 0.2f * u0);          // leaky_relu
  u1 = fmaxf(u1, 0.2f * u1);

  float t0 = head_reduce32(u0 * att0);
  float t1 = head_reduce32(u1 * att1);

  float p0 = __expf(t0);              // shift-free softmax (|alpha| small)
  float p1 = __expf(t1);
  S0 += p0;  S1 += p1;
  A0 = fmaf(p0, v0, A0);
  A1 = fmaf(p1, v1, A1);
}

__global__ __launch_bounds__(256, 2) void node_kernel(
    const float* __restrict__ x,
    const float* __restrict__ edge_attr,
    const float* __restrict__ We,
    const float* __restrict__ att,
    const float* __restrict__ bias_out,
    const float* __restrict__ gamma,
    const float* __restrict__ beta,
    const float* __restrict__ xl,
    const float* __restrict__ xr,
    const int* __restrict__ row_ptr,
    const int2* __restrict__ csr,
    float* __restrict__ out)
{
  const int lane = threadIdx.x & 63;
  const int n = blockIdx.x * 4 + (threadIdx.x >> 6);
  const int c0 = lane;
  const int c1 = lane + 64;

  float4 Wa0 = make_float4(We[ 0*128+c0], We[ 1*128+c0], We[ 2*128+c0], We[ 3*128+c0]);
  float4 Wa1 = make_float4(We[ 4*128+c0], We[ 5*128+c0], We[ 6*128+c0], We[ 7*128+c0]);
  float4 Wa2 = make_float4(We[ 8*128+c0], We[ 9*128+c0], We[10*128+c0], We[11*128+c0]);
  float4 Wa3 = make_float4(We[12*128+c0], We[13*128+c0], We[14*128+c0], We[15*128+c0]);
  float4 Wb0 = make_float4(We[ 0*128+c1], We[ 1*128+c1], We[ 2*128+c1], We[ 3*128+c1]);
  float4 Wb1 = make_float4(We[ 4*128+c1], We[ 5*128+c1], We[ 6*128+c1], We[ 7*128+c1]);
  float4 Wb2 = make_float4(We[ 8*128+c1], We[ 9*128+c1], We[10*128+c1], We[11*128+c1]);
  float4 Wb3 = make_float4(We[12*128+c1], We[13*128+c1], We[14*128+c1], We[15*128+c1]);

  const float att0 = att[c0], att1 = att[c1];
  const float xr0 = xr[(size_t)n * 128 + c0];
  const float xr1 = xr[(size_t)n * 128 + c1];

  const int i0 = __builtin_amdgcn_readfirstlane(row_ptr[n]);
  const int i1 = __builtin_amdgcn_readfirstlane(row_ptr[n + 1]);

  // 4 independent accumulator sets (ILP)
  float Sa0 = 0.f, Sa1 = 0.f, Aa0 = 0.f, Aa1 = 0.f;
  float Sb0 = 0.f, Sb1 = 0.f, Ab0 = 0.f, Ab1 = 0.f;
  float Sc0 = 0.f, Sc1 = 0.f, Ac0 = 0.f, Ac1 = 0.f;
  float Sd0 = 0.f, Sd1 = 0.f, Ad0 = 0.f, Ad1 = 0.f;

  int i = i0;
  for (; i + 3 < i1; i += 4) {
    // decode 4 edges up front
    int2 se0 = csr[i],     se1 = csr[i + 1];
    int2 se2 = csr[i + 2], se3 = csr[i + 3];
    int s0i = __builtin_amdgcn_readfirstlane(se0.x);
    int e0i = __builtin_amdgcn_readfirstlane(se0.y);
    int s1i = __builtin_amdgcn_readfirstlane(se1.x);
    int e1i = __builtin_amdgcn_readfirstlane(se1.y);
    int s2i = __builtin_amdgcn_readfirstlane(se2.x);
    int e2i = __builtin_amdgcn_readfirstlane(se2.y);
    int s3i = __builtin_amdgcn_readfirstlane(se3.x);
    int e3i = __builtin_amdgcn_readfirstlane(se3.y);

    // issue all gathers before any compute
    const float* p0 = xl + (size_t)s0i * 128;
    const float* p1 = xl + (size_t)s1i * 128;
    const float* p2 = xl + (size_t)s2i * 128;
    const float* p3 = xl + (size_t)s3i * 128;
    float v00 = p0[c0], v01 = p0[c1];
    float v10 = p1[c0], v11 = p1[c1];
    float v20 = p2[c0], v21 = p2[c1];
    float v30 = p3[c0], v31 = p3[c1];

    const float4* q0 = (const float4*)(edge_attr + (size_t)e0i * 16);
    const float4* q1 = (const float4*)(edge_attr + (size_t)e1i * 16);
    const float4* q2 = (const float4*)(edge_attr + (size_t)e2i * 16);
    const float4* q3 = (const float4*)(edge_attr + (size_t)e3i * 16);
    float4 a00 = q0[0], a01 = q0[1], a02 = q0[2], a03 = q0[3];
    float4 a10 = q1[0], a11 = q1[1], a12 = q1[2], a13 = q1[3];
    float4 a20 = q2[0], a21 = q2[1], a22 = q2[2], a23 = q2[3];
    float4 a30 = q3[0], a31 = q3[1], a32 = q3[2], a33 = q3[3];

    edge_compute(v00, v01, a00, a01, a02, a03, Wa0, Wa1, Wa2, Wa3, Wb0, Wb1, Wb2, Wb3,
                 att0, att1, xr0, xr1, Sa0, Sa1, Aa0, Aa1);
    edge_compute(v10, v11, a10, a11, a12, a13, Wa0, Wa1, Wa2, Wa3, Wb0, Wb1, Wb2, Wb3,
                 att0, att1, xr0, xr1, Sb0, Sb1, Ab0, Ab1);
    edge_compute(v20, v21, a20, a21, a22, a23, Wa0, Wa1, Wa2, Wa3, Wb0, Wb1, Wb2, Wb3,
                 att0, att1, xr0, xr1, Sc0, Sc1, Ac0, Ac1);
    edge_compute(v30, v31, a30, a31, a32, a33, Wa0, Wa1, Wa2, Wa3, Wb0, Wb1, Wb2, Wb3,
                 att0, att1, xr0, xr1, Sd0, Sd1, Ad0, Ad1);
  }
  for (; i < i1; ++i) {
    int2 se = csr[i];
    int s   = __builtin_amdgcn_readfirstlane(se.x);
    int eid = __builtin_amdgcn_readfirstlane(se.y);
    const float* xlp = xl + (size_t)s * 128;
    float v0 = xlp[c0], v1 = xlp[c1];
    const float4* ea4 = (const float4*)(edge_attr + (size_t)eid * 16);
    float4 a0 = ea4[0], a1 = ea4[1], a2 = ea4[2], a3 = ea4[3];
    edge_compute(v0, v1, a0, a1, a2, a3, Wa0, Wa1, Wa2, Wa3, Wb0, Wb1, Wb2, Wb3,
                 att0, att1, xr0, xr1, Sa0, Sa1, Aa0, Aa1);
  }

  float S0 = (Sa0 + Sb0) + (Sc0 + Sd0);
  float S1 = (Sa1 + Sb1) + (Sc1 + Sd1);
  float A0 = (Aa0 + Ab0) + (Ac0 + Ad0);
  float A1 = (Aa1 + Ab1) + (Ac1 + Ad1);

  float o0 = A0 / (S0 + 1e-16f) + bias_out[c0];
  float o1 = A1 / (S1 + 1e-16f) + bias_out[c1];
  float h0 = o0 > 0.f ? o0 : expm1f(o0);
  float h1 = o1 > 0.f ? o1 : expm1f(o1);
  float r0 = h0 + x[(size_t)n * 128 + c0];
  float r1 = h1 + x[(size_t)n * 128 + c1];

  // LayerNorm over 128 channels, in-wave (2 ch/lane)
  float s1 = r0 + r1;
  float s2 = r0 * r0 + r1 * r1;
  #pragma unroll
  for (int m = 1; m < 64; m <<= 1) {
    s1 += __shfl_xor(s1, m, 64);
    s2 += __shfl_xor(s2, m, 64);
  }
  float mean = s1 * (1.f / 128.f);
  float var  = s2 * (1.f / 128.f) - mean * mean;
  float rstd = rsqrtf(var + 1e-5f);
  out[(size_t)n * 128 + c0] = (r0 - mean) * rstd * gamma[c0] + beta[c0];
  out[(size_t)n * 128 + c1] = (r1 - mean) * rstd * gamma[c1] + beta[c1];
}

// ---------------- launch ----------------
extern "C" void kernel_launch(void* const* d_in, const int* in_sizes, int n_in,
                              void* d_out, int out_size, void* d_ws, size_t ws_size,
                              hipStream_t stream)
{
  const float* x         = (const float*)d_in[0];
  const int*   edge_idx  = (const int*)d_in[1];
  const float* edge_attr = (const float*)d_in[2];
  const float* Wl        = (const float*)d_in[3];
  const float* bl        = (const float*)d_in[4];
  const float* Wr        = (const float*)d_in[5];
  const float* br        = (const float*)d_in[6];
  const float* We        = (const float*)d_in[7];
  const float* att       = (const float*)d_in[8];
  const float* bias_out  = (const float*)d_in[9];
  const float* gamma     = (const float*)d_in[10];
  const float* beta      = (const float*)d_in[11];
  float* out = (float*)d_out;

  const int* src = edge_idx;        // edge_index[0]
  const int* dst = edge_idx + EE;   // edge_index[1]

  char* ws = (char*)d_ws;
  float* xl = (float*)ws;            ws += (size_t)NN * 128 * 4;   // 25.6 MB
  float* xr = (float*)ws;            ws += (size_t)NN * 128 * 4;   // 25.6 MB
  int* counts  = (int*)ws;           ws += (size_t)NN * 4;
  int* rank    = (int*)ws;           ws += (size_t)EE * 4;         // 4 MB
  int* row_ptr = (int*)ws;           ws += (size_t)(NN + 16) * 4;
  int2* csr = (int2*)ws;             ws += (size_t)EE * 8;         // 8 MB
  __bf16* img = (__bf16*)ws;                                       // 64 KB W image

  hipMemsetAsync(counts, 0, (size_t)NN * 4, stream);

  prep_kernel<<<1, 256, 0, stream>>>(Wl, Wr, img);
  lin_count_kernel<<<LINB + CNTB, 256, 0, stream>>>(
      x, img, bl, br, xl, xr, dst, counts, rank);
  scan_kernel<<<1, 1024, 0, stream>>>(counts, row_ptr);
  fill_kernel<<<CNTB, 256, 0, stream>>>(src, dst, rank, row_ptr, csr);
  node_kernel<<<NN / 4, 256, 0, stream>>>(x, edge_attr, We, att, bias_out, gamma, beta,
                                          xl, xr, row_ptr, csr, out);
}

// Round 13
// 427.474 us; speedup vs baseline: 1.0485x; 1.0485x over previous
//
#include <hip/hip_runtime.h>
#include <math.h>

#define NN 50000
#define EE 1000000

#define LINB 782                        // ceil(50000/64) blocks of 64 rows
#define CNT_THREADS (EE / 4)            // 250000 int4 units
#define CNTB ((CNT_THREADS + 255) / 256)  // 977

typedef float f32x4 __attribute__((ext_vector_type(4)));
typedef __bf16 bf16x8 __attribute__((ext_vector_type(8)));

typedef __attribute__((address_space(1))) const void gvoid_t;
typedef __attribute__((address_space(3))) void svoid_t;

// ---------------- K1: prep (block 0) + degree count/rank ----------------
// prep: image[(c*256 + k*2) ^ ((c&7)<<4)] = bf16(W[k][c]) — the LDS image lin copies linearly.
__global__ __launch_bounds__(256) void prep_count_kernel(
    const float* __restrict__ Wl, const float* __restrict__ Wr, __bf16* __restrict__ img,
    const int* __restrict__ dst, int* __restrict__ counts, int* __restrict__ rank)
{
  const int tid = threadIdx.x;

  if (blockIdx.x == 0) {
    // ---- prep W image (1 block) ----
    const int c  = tid;
    const int cc = c & 127;
    const float* __restrict__ Wsrc = (c < 128) ? Wl : Wr;
    for (int k0 = 0; k0 < 128; k0 += 8) {
      bf16x8 v;
      #pragma unroll
      for (int j = 0; j < 8; ++j) v[j] = (__bf16)Wsrc[(size_t)(k0 + j) * 128 + cc];
      int byte = (c * 256 + k0 * 2) ^ ((c & 7) << 4);
      *(bf16x8*)((char*)img + byte) = v;
    }
    return;
  }

  // ---- count + rank (single atomic pass) ----
  int t = (blockIdx.x - 1) * 256 + tid;
  if (t < CNT_THREADS) {
    int4 d4 = ((const int4*)dst)[t];
    int4 r4;
    r4.x = atomicAdd(&counts[d4.x], 1);
    r4.y = atomicAdd(&counts[d4.y], 1);
    r4.z = atomicAdd(&counts[d4.z], 1);
    r4.w = atomicAdd(&counts[d4.w], 1);
    ((int4*)rank)[t] = r4;
  }
}

// ---------------- K2: scan — exclusive prefix over counts -> row_ptr ----------------
__global__ __launch_bounds__(1024) void scan_kernel(const int* __restrict__ counts,
                                                    int* __restrict__ row_ptr)
{
  __shared__ int s[1024];
  const int t = threadIdx.x;
  const int CH = (NN + 1023) / 1024;   // 49
  const int base = t * CH;
  int sum = 0;
  for (int j = 0; j < CH; ++j) {
    int idx = base + j;
    if (idx < NN) sum += counts[idx];
  }
  s[t] = sum;
  __syncthreads();
  for (int ofs = 1; ofs < 1024; ofs <<= 1) {
    int v = (t >= ofs) ? s[t - ofs] : 0;
    __syncthreads();
    s[t] += v;
    __syncthreads();
  }
  int run = s[t] - sum;
  for (int j = 0; j < CH; ++j) {
    int idx = base + j;
    if (idx < NN) { row_ptr[idx] = run; run += counts[idx]; }
  }
  if (t == 1023) row_ptr[NN] = s[1023];
}

// ---------------- K3: lin GEMM (blocks 0..LINB-1)  ||  fill (blocks LINB..) ----------------
__global__ __launch_bounds__(256) void lin_fill_kernel(
    const float* __restrict__ x,
    const __bf16* __restrict__ img,
    const float* __restrict__ bl, const float* __restrict__ br,
    float* __restrict__ xl, float* __restrict__ xr,
    const int* __restrict__ src, const int* __restrict__ dst,
    const int* __restrict__ rank, const int* __restrict__ row_ptr,
    int2* __restrict__ csr)
{
  const int tid = threadIdx.x;

  if (blockIdx.x >= LINB) {
    // ---- fill: atomic-free CSR placement via rank ----
    int t = (blockIdx.x - LINB) * 256 + tid;
    if (t < CNT_THREADS) {
      int4 s4 = ((const int4*)src)[t];
      int4 d4 = ((const int4*)dst)[t];
      int4 r4 = ((const int4*)rank)[t];
      int e0 = t * 4;
      csr[row_ptr[d4.x] + r4.x] = make_int2(s4.x, e0 + 0);
      csr[row_ptr[d4.y] + r4.y] = make_int2(s4.y, e0 + 1);
      csr[row_ptr[d4.z] + r4.z] = make_int2(s4.z, e0 + 2);
      csr[row_ptr[d4.w] + r4.w] = make_int2(s4.w, e0 + 3);
    }
    return;
  }

  // ---- MFMA GEMM: C[64 rows][256 cols], cols 0-127 -> xl, 128-255 -> xr ----
  __shared__ __bf16 wt[256 * 128];   // 64 KB, linear copy of pre-swizzled image

  {
    const int wv = tid >> 6, ln = tid & 63;
    #pragma unroll
    for (int it = 0; it < 16; ++it) {
      int off = wv * 16384 + it * 1024;       // wave-uniform LDS offset
      __builtin_amdgcn_global_load_lds(
          (gvoid_t*)((const char*)img + off + ln * 16),
          (svoid_t*)((char*)wt + off), 16, 0, 0);
    }
  }
  __syncthreads();

  const int wave = tid >> 6;
  const int lane = tid & 63;
  const int l15  = lane & 15;
  const int lhi  = lane >> 4;   // 0..3

  const int row_a   = blockIdx.x * 64 + wave * 16 + l15;   // A-fragment row
  const int row_a_c = row_a < NN ? row_a : NN - 1;         // clamp (stores guarded)

  f32x4 acc[16];
  #pragma unroll
  for (int t = 0; t < 16; ++t) acc[t] = (f32x4)0.f;

  #pragma unroll
  for (int kk = 0; kk < 4; ++kk) {
    const float* ap = x + (size_t)row_a_c * 128 + kk * 32 + lhi * 8;
    float4 a0 = *(const float4*)ap;
    float4 a1 = *(const float4*)(ap + 4);
    bf16x8 af;
    af[0] = (__bf16)a0.x; af[1] = (__bf16)a0.y; af[2] = (__bf16)a0.z; af[3] = (__bf16)a0.w;
    af[4] = (__bf16)a1.x; af[5] = (__bf16)a1.y; af[6] = (__bf16)a1.z; af[7] = (__bf16)a1.w;
    #pragma unroll
    for (int nt = 0; nt < 16; ++nt) {
      int col  = nt * 16 + l15;
      int byte = (col * 256 + (kk * 32 + lhi * 8) * 2) ^ ((col & 7) << 4);
      bf16x8 bf = *(const bf16x8*)((const char*)wt + byte);
      acc[nt] = __builtin_amdgcn_mfma_f32_16x16x32_bf16(af, bf, acc[nt], 0, 0, 0);
    }
  }

  // epilogue: C layout col=lane&15, row=(lane>>4)*4+j  [m89-verified]
  const int row_base = blockIdx.x * 64 + wave * 16 + lhi * 4;
  #pragma unroll
  for (int nt = 0; nt < 16; ++nt) {
    int col = nt * 16 + l15;
    float bv = (col < 128) ? bl[col] : br[col - 128];
    float* dp = (col < 128) ? (xl + col) : (xr + (col - 128));
    #pragma unroll
    for (int j = 0; j < 4; ++j) {
      int r = row_base + j;
      if (r < NN) dp[(size_t)r * 128] = acc[nt][j] + bv;
    }
  }
}

// ---------------- K4: fused per-node kernel (exact round-10 form, 144.0 µs measured) ----------------
template<int CTRL>
__device__ __forceinline__ float dpp_add(float v)
{
  int y = __builtin_amdgcn_update_dpp(0, __float_as_int(v), CTRL, 0xF, 0xF, true);
  return v + __int_as_float(y);
}

__device__ __forceinline__ float head_reduce32(float v)
{
  v = dpp_add<0xB1>(v);    // quad_perm xor1
  v = dpp_add<0x4E>(v);    // quad_perm xor2
  v = dpp_add<0x141>(v);   // row_half_mirror
  v = dpp_add<0x140>(v);   // row_mirror
  int y = __builtin_amdgcn_ds_swizzle(__float_as_int(v), 0x401F); // xor16 within 32
  return v + __int_as_float(y);
}

__device__ __forceinline__ void edge_compute(
    float v0, float v1, float4 e0, float4 e1, float4 e2, float4 e3,
    float4 Wa0, float4 Wa1, float4 Wa2, float4 Wa3,
    float4 Wb0, float4 Wb1, float4 Wb2, float4 Wb3,
    float att0, float att1, float xr0, float xr1,
    float& S0, float& S1, float& A0, float& A1)
{
  float s0 = xr0, s1 = xr1;
  s0 = fmaf(e0.x, Wa0.x, s0); s1 = fmaf(e0.x, Wb0.x, s1);
  s0 = fmaf(e0.y, Wa0.y, s0); s1 = fmaf(e0.y, Wb0.y, s1);
  s0 = fmaf(e0.z, Wa0.z, s0); s1 = fmaf(e0.z, Wb0.z, s1);
  s0 = fmaf(e0.w, Wa0.w, s0); s1 = fmaf(e0.w, Wb0.w, s1);
  s0 = fmaf(e1.x, Wa1.x, s0); s1 = fmaf(e1.x, Wb1.x, s1);
  s0 = fmaf(e1.y, Wa1.y, s0); s1 = fmaf(e1.y, Wb1.y, s1);
  s0 = fmaf(e1.z, Wa1.z, s0); s1 = fmaf(e1.z, Wb1.z, s1);
  s0 = fmaf(e1.w, Wa1.w, s0); s1 = fmaf(e1.w, Wb1.w, s1);
  s0 = fmaf(e2.x, Wa2.x, s0); s1 = fmaf(e2.x, Wb2.x, s1);
  s0 = fmaf(e2.y, Wa2.y, s0); s1 = fmaf(e2.y, Wb2.y, s1);
  s0 = fmaf(e2.z, Wa2.z, s0); s1 = fmaf(e2.z, Wb2.z, s1);
  s0 = fmaf(e2.w, Wa2.w, s0); s1 = fmaf(e2.w, Wb2.w, s1);
  s0 = fmaf(e3.x, Wa3.x, s0); s1 = fmaf(e3.x, Wb3.x, s1);
  s0 = fmaf(e3.y, Wa3.y, s0); s1 = fmaf(e3.y, Wb3.y, s1);
  s0 = fmaf(e3.z, Wa3.z, s0); s1 = fmaf(e3.z, Wb3.z, s1);
  s0 = fmaf(e3.w, Wa3.w, s0); s1 = fmaf(e3.w, Wb3.w, s1);

  float u0 = v0 + s0;
  float u1 = v1 + s1;
  u0 = fmaxf(u0, 0.2f * u0);          // leaky_relu
  u1 = fmaxf(u1, 0.2f * u1);

  float t0 = head_reduce32(u0 * att0);
  float t1 = head_reduce32(u1 * att1);

  float p0 = __expf(t0);              // shift-free softmax (|alpha| small)
  float p1 = __expf(t1);
  S0 += p0;  S1 += p1;
  A0 = fmaf(p0, v0, A0);
  A1 = fmaf(p1, v1, A1);
}

__global__ __launch_bounds__(256, 2) void node_kernel(
    const float* __restrict__ x,
    const float* __restrict__ edge_attr,
    const float* __restrict__ We,
    const float* __restrict__ att,
    const float* __restrict__ bias_out,
    const float* __restrict__ gamma,
    const float* __restrict__ beta,
    const float* __restrict__ xl,
    const float* __restrict__ xr,
    const int* __restrict__ row_ptr,
    const int2* __restrict__ csr,
    float* __restrict__ out)
{
  const int lane = threadIdx.x & 63;
  const int n = blockIdx.x * 4 + (threadIdx.x >> 6);
  const int c0 = lane;
  const int c1 = lane + 64;

  float4 Wa0 = make_float4(We[ 0*128+c0], We[ 1*128+c0], We[ 2*128+c0], We[ 3*128+c0]);
  float4 Wa1 = make_float4(We[ 4*128+c0], We[ 5*128+c0], We[ 6*128+c0], We[ 7*128+c0]);
  float4 Wa2 = make_float4(We[ 8*128+c0], We[ 9*128+c0], We[10*128+c0], We[11*128+c0]);
  float4 Wa3 = make_float4(We[12*128+c0], We[13*128+c0], We[14*128+c0], We[15*128+c0]);
  float4 Wb0 = make_float4(We[ 0*128+c1], We[ 1*128+c1], We[ 2*128+c1], We[ 3*128+c1]);
  float4 Wb1 = make_float4(We[ 4*128+c1], We[ 5*128+c1], We[ 6*128+c1], We[ 7*128+c1]);
  float4 Wb2 = make_float4(We[ 8*128+c1], We[ 9*128+c1], We[10*128+c1], We[11*128+c1]);
  float4 Wb3 = make_float4(We[12*128+c1], We[13*128+c1], We[14*128+c1], We[15*128+c1]);

  const float att0 = att[c0], att1 = att[c1];
  const float xr0 = xr[(size_t)n * 128 + c0];
  const float xr1 = xr[(size_t)n * 128 + c1];

  const int i0 = __builtin_amdgcn_readfirstlane(row_ptr[n]);
  const int i1 = __builtin_amdgcn_readfirstlane(row_ptr[n + 1]);

  float S0a = 0.f, S1a = 0.f, A0a = 0.f, A1a = 0.f;
  float S0b = 0.f, S1b = 0.f, A0b = 0.f, A1b = 0.f;

  int i = i0;
  for (; i + 1 < i1; i += 2) {
    int2 sea = csr[i];
    int2 seb = csr[i + 1];
    int sa  = __builtin_amdgcn_readfirstlane(sea.x);
    int eia = __builtin_amdgcn_readfirstlane(sea.y);
    int sb  = __builtin_amdgcn_readfirstlane(seb.x);
    int eib = __builtin_amdgcn_readfirstlane(seb.y);

    const float* xla = xl + (size_t)sa * 128;
    const float* xlb = xl + (size_t)sb * 128;
    float va0 = xla[c0], va1 = xla[c1];
    float vb0 = xlb[c0], vb1 = xlb[c1];

    const float4* eaa = (const float4*)(edge_attr + (size_t)eia * 16);
    const float4* eab = (const float4*)(edge_attr + (size_t)eib * 16);
    float4 a0 = eaa[0], a1 = eaa[1], a2 = eaa[2], a3 = eaa[3];
    float4 b0 = eab[0], b1 = eab[1], b2 = eab[2], b3 = eab[3];

    edge_compute(va0, va1, a0, a1, a2, a3,
                 Wa0, Wa1, Wa2, Wa3, Wb0, Wb1, Wb2, Wb3,
                 att0, att1, xr0, xr1, S0a, S1a, A0a, A1a);
    edge_compute(vb0, vb1, b0, b1, b2, b3,
                 Wa0, Wa1, Wa2, Wa3, Wb0, Wb1, Wb2, Wb3,
                 att0, att1, xr0, xr1, S0b, S1b, A0b, A1b);
  }
  if (i < i1) {
    int2 se = csr[i];
    int s   = __builtin_amdgcn_readfirstlane(se.x);
    int eid = __builtin_amdgcn_readfirstlane(se.y);
    const float* xlp = xl + (size_t)s * 128;
    float v0 = xlp[c0], v1 = xlp[c1];
    const float4* ea4 = (const float4*)(edge_attr + (size_t)eid * 16);
    float4 a0 = ea4[0], a1 = ea4[1], a2 = ea4[2], a3 = ea4[3];
    edge_compute(v0, v1, a0, a1, a2, a3,
                 Wa0, Wa1, Wa2, Wa3, Wb0, Wb1, Wb2, Wb3,
                 att0, att1, xr0, xr1, S0a, S1a, A0a, A1a);
  }

  float S0 = S0a + S0b, S1 = S1a + S1b;
  float A0 = A0a + A0b, A1 = A1a + A1b;

  float o0 = A0 / (S0 + 1e-16f) + bias_out[c0];
  float o1 = A1 / (S1 + 1e-16f) + bias_out[c1];
  float h0 = o0 > 0.f ? o0 : expm1f(o0);
  float h1 = o1 > 0.f ? o1 : expm1f(o1);
  float r0 = h0 + x[(size_t)n * 128 + c0];
  float r1 = h1 + x[(size_t)n * 128 + c1];

  // LayerNorm over 128 channels, in-wave (2 ch/lane)
  float s1 = r0 + r1;
  float s2 = r0 * r0 + r1 * r1;
  #pragma unroll
  for (int m = 1; m < 64; m <<= 1) {
    s1 += __shfl_xor(s1, m, 64);
    s2 += __shfl_xor(s2, m, 64);
  }
  float mean = s1 * (1.f / 128.f);
  float var  = s2 * (1.f / 128.f) - mean * mean;
  float rstd = rsqrtf(var + 1e-5f);
  out[(size_t)n * 128 + c0] = (r0 - mean) * rstd * gamma[c0] + beta[c0];
  out[(size_t)n * 128 + c1] = (r1 - mean) * rstd * gamma[c1] + beta[c1];
}

// ---------------- launch ----------------
extern "C" void kernel_launch(void* const* d_in, const int* in_sizes, int n_in,
                              void* d_out, int out_size, void* d_ws, size_t ws_size,
                              hipStream_t stream)
{
  const float* x         = (const float*)d_in[0];
  const int*   edge_idx  = (const int*)d_in[1];
  const float* edge_attr = (const float*)d_in[2];
  const float* Wl        = (const float*)d_in[3];
  const float* bl        = (const float*)d_in[4];
  const float* Wr        = (const float*)d_in[5];
  const float* br        = (const float*)d_in[6];
  const float* We        = (const float*)d_in[7];
  const float* att       = (const float*)d_in[8];
  const float* bias_out  = (const float*)d_in[9];
  const float* gamma     = (const float*)d_in[10];
  const float* beta      = (const float*)d_in[11];
  float* out = (float*)d_out;

  const int* src = edge_idx;        // edge_index[0]
  const int* dst = edge_idx + EE;   // edge_index[1]

  char* ws = (char*)d_ws;
  float* xl = (float*)ws;            ws += (size_t)NN * 128 * 4;   // 25.6 MB
  float* xr = (float*)ws;            ws += (size_t)NN * 128 * 4;   // 25.6 MB
  int* counts  = (int*)ws;           ws += (size_t)NN * 4;
  int* rank    = (int*)ws;           ws += (size_t)EE * 4;         // 4 MB
  int* row_ptr = (int*)ws;           ws += (size_t)(NN + 16) * 4;
  int2* csr = (int2*)ws;             ws += (size_t)EE * 8;         // 8 MB
  __bf16* img = (__bf16*)ws;                                       // 64 KB W image

  hipMemsetAsync(counts, 0, (size_t)NN * 4, stream);

  prep_count_kernel<<<CNTB + 1, 256, 0, stream>>>(Wl, Wr, img, dst, counts, rank);
  scan_kernel<<<1, 1024, 0, stream>>>(counts, row_ptr);
  lin_fill_kernel<<<LINB + CNTB, 256, 0, stream>>>(
      x, img, bl, br, xl, xr, src, dst, rank, row_ptr, csr);
  node_kernel<<<NN / 4, 256, 0, stream>>>(x, edge_attr, We, att, bias_out, gamma, beta,
                                          xl, xr, row_ptr, csr, out);
}